// Round 7
// baseline (63.432 us; speedup 1.0000x reference)
//
#include <hip/hip_runtime.h>

typedef int i32x4 __attribute__((ext_vector_type(4)));

#define C_IN 128
#define HW 56
#define PIX 3136            // 56*56
#define NPLANE 401408       // 128*3136

// ---------------- fused stats: blocks 0..1023 = BN (c,slice), 1024..1087 = weight chunks ----------------
__global__ __launch_bounds__(256) void stats_k(const float* __restrict__ x,
                                               const float* __restrict__ w,
                                               double* __restrict__ bnpart,
                                               double* __restrict__ wpart) {
  const int b = blockIdx.x, tid = threadIdx.x;
  double s = 0.0, s2 = 0.0;
  if (b < 1024) {
    const int c = b & 127, sl = b >> 7;
    for (int n = sl * 4; n < sl * 4 + 4; ++n) {
      const float4* p = (const float4*)(x + (size_t)(n * C_IN + c) * PIX);
      for (int i = tid; i < PIX / 4; i += 256) {
        float4 v = p[i];
        s  += (double)v.x + (double)v.y + (double)v.z + (double)v.w;
        s2 += (double)v.x * v.x + (double)v.y * v.y + (double)v.z * v.z + (double)v.w * v.w;
      }
    }
  } else {
    const int wb = b - 1024;
    const float4* p = (const float4*)w;
    for (int i = wb * 576 + tid; i < (wb + 1) * 576; i += 256) {
      float4 v = p[i];
      s  += (double)v.x + (double)v.y + (double)v.z + (double)v.w;
      s2 += (double)v.x * v.x + (double)v.y * v.y + (double)v.z * v.z + (double)v.w * v.w;
    }
  }
  __shared__ double red[8];
  const int lane = tid & 63, wv = tid >> 6;
  for (int off = 32; off; off >>= 1) { s += __shfl_down(s, off); s2 += __shfl_down(s2, off); }
  if (lane == 0) { red[wv * 2] = s; red[wv * 2 + 1] = s2; }
  __syncthreads();
  if (tid == 0) {
    // bnpart layout [c][sl] (consumer reads c*8+sl)
    double* dst = (b < 1024) ? (bnpart + ((b & 127) * 8 + (b >> 7)) * 2)
                             : (wpart + (b - 1024) * 2);
    dst[0] = red[0] + red[2] + red[4] + red[6];
    dst[1] = red[1] + red[3] + red[5] + red[7];
  }
}

// ---------------- quantize weights -> wq[rs][128 oc][128 c] int8, LINEAR ----------------
__global__ __launch_bounds__(128) void quant_w_k(const float* __restrict__ w,
                                                 const double* __restrict__ wpart,
                                                 signed char* __restrict__ wq,
                                                 float* __restrict__ stepp) {
  const int oc = blockIdx.x, tid = threadIdx.x;
  __shared__ float steps;
  __shared__ __align__(16) signed char lds[9 * 128];
  if (tid < 64) {
    double s = wpart[tid * 2], s2 = wpart[tid * 2 + 1];
    for (int off = 32; off; off >>= 1) { s += __shfl_down(s, off); s2 += __shfl_down(s2, off); }
    if (tid == 0) {
      const double mean = s / 147456.0;
      const double var = s2 / 147456.0 - mean * mean;
      steps = 0.996f * (float)sqrt(var);
      if (oc == 0) stepp[0] = steps;
    }
  }
  __syncthreads();
  const float step = steps;
  for (int i = tid; i < 1152; i += 128) {
    const int c = i / 9, rs = i - c * 9;
    const float v = w[(size_t)(oc * C_IN + c) * 9 + rs];
    float t = 2.f * rintf(v / step + 0.5f) - 1.f;  // iw2 odd ints
    t = fminf(fmaxf(t, -3.f), 3.f);
    lds[rs * 128 + c] = (signed char)(int)t;
  }
  __syncthreads();
  for (int i = tid; i < 72; i += 128) {  // 9 rs * 8 uint4, coalesced linear writes
    const int rs = i >> 3, c16 = i & 7;
    *(uint4*)(wq + rs * 16384 + oc * 128 + c16 * 16) = *(const uint4*)(lds + rs * 128 + c16 * 16);
  }
}

// ---------------- fused conv: BN-affine + act-quant + implicit GEMM ----------------
// block = 128 oc x 224 px (4 out rows); 4 waves; 2 blocks/CU; weights direct from L2.
__global__ __launch_bounds__(256, 2) void conv_k(const float* __restrict__ x,
                                                 const double* __restrict__ bnpart,
                                                 const float* __restrict__ gamma,
                                                 const float* __restrict__ beta,
                                                 const signed char* __restrict__ wq,
                                                 const float* __restrict__ stepp,
                                                 float* __restrict__ out) {
  __shared__ __align__(16) signed char Al[45056];  // 6 padded rows x 58 x 128, XOR-swizzled
  __shared__ float2 aff[128];
  // XCD-bijective swizzle: 448 = 8 XCDs x 56; consecutive vid (same n, adjacent rg) share an XCD L2.
  const int bid = blockIdx.x;
  const int vid = (bid & 7) * 56 + (bid >> 3);
  const int n = vid / 14;
  const int rg = vid - n * 14;
  const int tid = threadIdx.x;
  const int wv = tid >> 6, lane = tid & 63;
  const int lr = lane & 15, q4 = lane >> 4;
  const int kq = q4 * 16;
  const int ohalf = (wv & 1) * 64;
  const int phalf = (wv >> 1) * 112;

  // ---- phase A: per-channel affine (from bnpart) + border zeros (disjoint writes) ----
  if (tid < 128) {
    double s = 0.0, s2 = 0.0;
    for (int i = 0; i < 8; ++i) { s += bnpart[(tid * 8 + i) * 2]; s2 += bnpart[(tid * 8 + i) * 2 + 1]; }
    const double mean = s / 100352.0;
    const double var = s2 / 100352.0 - mean * mean;
    const double inv = 1.0 / sqrt(var + 1e-3);
    aff[tid] = make_float2((float)((double)gamma[tid] * inv),
                           (float)((double)beta[tid] - mean * inv * (double)gamma[tid]));
  }
  const uint4 z4 = make_uint4(0, 0, 0, 0);
  if (tid < 96) {  // cols 0 and 57, all 6 rows
    const int j = tid >> 4, rem = tid & 15;
    const int px = j * 58 + (rem >> 3) * 57;
    *(uint4*)(Al + (((px * 128) + (rem & 7) * 16) ^ ((px & 7) << 4))) = z4;
  }
  if (rg == 0)   // padded row 0 (cols 1..56)
    for (int i = tid; i < 448; i += 256) {
      const int px = 1 + (i >> 3);
      *(uint4*)(Al + ((px * 128 + (i & 7) * 16) ^ ((px & 7) << 4))) = z4;
    }
  if (rg == 13)  // padded row 57 (cols 1..56)
    for (int i = tid; i < 448; i += 256) {
      const int px = 5 * 58 + 1 + (i >> 3);
      *(uint4*)(Al + ((px * 128 + (i & 7) * 16) ^ ((px & 7) << 4))) = z4;
    }
  __syncthreads();  // aff visible

  // ---- phase B: stage + quantize interior (reads x from L3) ----
  for (int j = 0; j < 6; ++j) {
    const int hp = rg * 4 + j;
    if (hp < 1 || hp > 56) continue;
    const float* xrowb = x + (size_t)n * NPLANE + (size_t)(hp - 1) * HW;
    for (int i = tid; i < 1792; i += 256) {  // 32 c-groups x 56 w
      const int c4 = i / 56, w = i - c4 * 56;
      const float* xp = xrowb + (size_t)(c4 * 4) * PIX + w;
      unsigned int pack = 0;
#pragma unroll
      for (int k = 0; k < 4; ++k) {
        const float2 af = aff[c4 * 4 + k];
        const float xn = fmaf(xp[(size_t)k * PIX], af.x, af.y);
        const float y = fminf(fmaxf(xn, 0.f), 1.614f);       // clip [0, 3*0.538]
        pack |= (unsigned int)(int)rintf(y * (1.f / 0.538f)) << (8 * k);
      }
      const int px = j * 58 + 1 + w;
      *(unsigned int*)(Al + ((px * 128 + c4 * 4) ^ ((px & 7) << 4))) = pack;
    }
  }
  __syncthreads();  // Al ready; no more barriers

  int pbase[7];
#pragma unroll
  for (int pf = 0; pf < 7; ++pf) {
    const int po = phalf + pf * 16 + lr;   // 0..223
    pbase[pf] = (po / 56) * 58 + po % 56;
  }

  i32x4 acc[7][4];
#pragma unroll
  for (int i = 0; i < 7; ++i)
#pragma unroll
    for (int j = 0; j < 4; ++j) acc[i][j] = (i32x4){0, 0, 0, 0};

  // ---- phase C: K-loop, weights straight from L2 (no LDS, no barriers) ----
  for (int rs = 0; rs < 9; ++rs) {
    const int r = rs / 3, s = rs - 3 * r;
    const int poff = r * 58 + s;
    const signed char* wrow = wq + rs * 16384;
#pragma unroll
    for (int k64 = 0; k64 < 2; ++k64) {
      const int kb = k64 * 64 + kq;
      i32x4 wf[4];
#pragma unroll
      for (int of = 0; of < 4; ++of)
        wf[of] = *(const i32x4*)(wrow + (ohalf + of * 16 + lr) * 128 + kb);
#pragma unroll
      for (int pf = 0; pf < 7; ++pf) {
        const int p = pbase[pf] + poff;
        const i32x4 bf = *(const i32x4*)(Al + ((p * 128 + kb) ^ ((p & 7) << 4)));
        acc[pf][0] = __builtin_amdgcn_mfma_i32_16x16x64_i8(wf[0], bf, acc[pf][0], 0, 0, 0);
        acc[pf][1] = __builtin_amdgcn_mfma_i32_16x16x64_i8(wf[1], bf, acc[pf][1], 0, 0, 0);
        acc[pf][2] = __builtin_amdgcn_mfma_i32_16x16x64_i8(wf[2], bf, acc[pf][2], 0, 0, 0);
        acc[pf][3] = __builtin_amdgcn_mfma_i32_16x16x64_i8(wf[3], bf, acc[pf][3], 0, 0, 0);
      }
    }
  }

  const float oscale = 0.269f * stepp[0];  // a_step * w_step/2
  float* outn = out + (size_t)n * NPLANE + (size_t)rg * 224;  // 4-row slab base
#pragma unroll
  for (int pf = 0; pf < 7; ++pf) {
    const int po = phalf + pf * 16 + lr;
    float* op = outn + po;
#pragma unroll
    for (int of = 0; of < 4; ++of) {
      const int oc = ohalf + of * 16 + q4 * 4;
#pragma unroll
      for (int q = 0; q < 4; ++q)
        op[(size_t)(oc + q) * PIX] = (float)acc[pf][of][q] * oscale;
    }
  }
}

extern "C" void kernel_launch(void* const* d_in, const int* in_sizes, int n_in,
                              void* d_out, int out_size, void* d_ws, size_t ws_size,
                              hipStream_t stream) {
  const float* x = (const float*)d_in[0];
  const float* gamma = (const float*)d_in[1];
  const float* beta = (const float*)d_in[2];
  const float* w = (const float*)d_in[3];
  float* out = (float*)d_out;
  char* ws = (char*)d_ws;

  double* bnpart = (double*)(ws);                // 16384 B
  double* wpart = (double*)(ws + 16384);         // 1024 B
  float* stepp = (float*)(ws + 17408);           // 4 B
  signed char* wq = (signed char*)(ws + 18432);  // 9*128*128 = 147456 B

  stats_k<<<1088, 256, 0, stream>>>(x, w, bnpart, wpart);
  quant_w_k<<<128, 128, 0, stream>>>(w, wpart, wq, stepp);
  conv_k<<<448, 256, 0, stream>>>(x, bnpart, gamma, beta, wq, stepp, out);
}

// Round 8
// 59.435 us; speedup vs baseline: 1.0672x; 1.0672x over previous
//
#include <hip/hip_runtime.h>

typedef int i32x4 __attribute__((ext_vector_type(4)));

#define C_IN 128
#define HW 56
#define PIX 3136            // 56*56
#define NPLANE 401408       // 128*3136
#define PROWB 7424          // 58*128 bytes per padded row (i8)
#define APAD_NSTRIDE 430592 // 58*58*128

// direct global->LDS DMA, 16B per lane, linear dest (wave-uniform base + lane*16)
static __device__ __forceinline__ void gload_lds16(const void* g, void* l) {
  __builtin_amdgcn_global_load_lds((__attribute__((address_space(1))) unsigned int*)g,
                                   (__attribute__((address_space(3))) unsigned int*)l, 16, 0, 0);
}

// ---------------- fused stats: blocks 0..1023 = BN (c,slice), 1024..1087 = weight chunks ----------------
__global__ __launch_bounds__(256) void stats_k(const float* __restrict__ x,
                                               const float* __restrict__ w,
                                               double* __restrict__ bnpart,
                                               double* __restrict__ wpart) {
  const int b = blockIdx.x, tid = threadIdx.x;
  double s = 0.0, s2 = 0.0;
  if (b < 1024) {
    const int c = b & 127, sl = b >> 7;
    for (int n = sl * 4; n < sl * 4 + 4; ++n) {
      const float4* p = (const float4*)(x + (size_t)(n * C_IN + c) * PIX);
      for (int i = tid; i < PIX / 4; i += 256) {
        float4 v = p[i];
        s  += (double)v.x + (double)v.y + (double)v.z + (double)v.w;
        s2 += (double)v.x * v.x + (double)v.y * v.y + (double)v.z * v.z + (double)v.w * v.w;
      }
    }
  } else {
    const int wb = b - 1024;
    const float4* p = (const float4*)w;
    for (int i = wb * 576 + tid; i < (wb + 1) * 576; i += 256) {
      float4 v = p[i];
      s  += (double)v.x + (double)v.y + (double)v.z + (double)v.w;
      s2 += (double)v.x * v.x + (double)v.y * v.y + (double)v.z * v.z + (double)v.w * v.w;
    }
  }
  __shared__ double red[8];
  const int lane = tid & 63, wv = tid >> 6;
  for (int off = 32; off; off >>= 1) { s += __shfl_down(s, off); s2 += __shfl_down(s2, off); }
  if (lane == 0) { red[wv * 2] = s; red[wv * 2 + 1] = s2; }
  __syncthreads();
  if (tid == 0) {
    // bnpart layout [c][sl] (consumer reads c*8+sl)
    double* dst = (b < 1024) ? (bnpart + ((b & 127) * 8 + (b >> 7)) * 2)
                             : (wpart + (b - 1024) * 2);
    dst[0] = red[0] + red[2] + red[4] + red[6];
    dst[1] = red[1] + red[3] + red[5] + red[7];
  }
}

// ---------------- fused quantize: y<32 = act rows (pre-swizzled apad), y==32 = weights (LINEAR wq) ----------------
__global__ __launch_bounds__(256) void quant_k(const float* __restrict__ x,
                                               const float* __restrict__ w,
                                               const float* __restrict__ gamma,
                                               const float* __restrict__ beta,
                                               const double* __restrict__ bnpart,
                                               const double* __restrict__ wpart,
                                               signed char* __restrict__ apad,
                                               signed char* __restrict__ wq,
                                               float* __restrict__ stepp) {
  const int tid = threadIdx.x;
  if (blockIdx.y == 32) {
    // ---- weight path: block bx handles oc in {bx, bx+58, bx+116} ----
    const int bx = blockIdx.x;
    __shared__ float steps;
    __shared__ __align__(16) signed char wl[3 * 1152];   // [oi][rs][c]
    if (tid < 64) {
      double s = wpart[tid * 2], s2 = wpart[tid * 2 + 1];
      for (int off = 32; off; off >>= 1) { s += __shfl_down(s, off); s2 += __shfl_down(s2, off); }
      if (tid == 0) {
        const double mean = s / 147456.0;
        const double var = s2 / 147456.0 - mean * mean;
        steps = 0.996f * (float)sqrt(var);
        if (bx == 0) stepp[0] = steps;
      }
    }
    __syncthreads();
    const float step = steps;
    for (int i = tid; i < 3456; i += 256) {
      const int oi = i / 1152, rem = i - oi * 1152;
      const int oc = bx + oi * 58;
      if (oc < 128) {
        const int c = rem / 9, rs = rem - c * 9;
        const float v = w[(size_t)(oc * C_IN + c) * 9 + rs];
        float t = 2.f * rintf(v / step + 0.5f) - 1.f;  // iw2 odd ints
        t = fminf(fmaxf(t, -3.f), 3.f);
        wl[oi * 1152 + rs * 128 + c] = (signed char)(int)t;
      }
    }
    __syncthreads();
    for (int i = tid; i < 216; i += 256) {  // 3 oc * 9 rs * 8 uint4, LINEAR layout
      const int oi = i / 72, rem = i - oi * 72;
      const int oc = bx + oi * 58;
      if (oc < 128) {
        const int rs = rem >> 3, c16 = rem & 7;
        *(uint4*)(wq + rs * 16384 + oc * 128 + c16 * 16) =
            *(const uint4*)(wl + oi * 1152 + rs * 128 + c16 * 16);
      }
    }
    return;
  }
  // ---- act path: padded row hh of image n ----
  const int hh = blockIdx.x;
  const int n = blockIdx.y;
  __shared__ float2 aff[128];
  __shared__ __align__(16) signed char lds[58 * 144];
  if (tid < 128) {
    double s = 0.0, s2 = 0.0;
    for (int i = 0; i < 8; ++i) { s += bnpart[(tid * 8 + i) * 2]; s2 += bnpart[(tid * 8 + i) * 2 + 1]; }
    const double mean = s / 100352.0;
    const double var = s2 / 100352.0 - mean * mean;
    const double inv = 1.0 / sqrt(var + 1e-3);
    aff[tid] = make_float2((float)((double)gamma[tid] * inv),
                           (float)((double)beta[tid] - mean * inv * (double)gamma[tid]));
  }
  uint4* lds4 = (uint4*)lds;
  for (int i = tid; i < 58 * 144 / 16; i += 256) lds4[i] = make_uint4(0, 0, 0, 0);
  __syncthreads();
  if (hh >= 1 && hh <= 56) {
    const float* xp = x + (size_t)n * NPLANE + (hh - 1) * HW;
    for (int i = tid; i < 1792; i += 256) {   // 128 c x 14 w-quads, float4 loads
      const int c = i / 14, w4 = (i - c * 14) * 4;
      const float4 v = *(const float4*)(xp + (size_t)c * PIX + w4);
      const float2 af = aff[c];
      const float k = 1.f / 0.538f;
      lds[(w4 + 1) * 144 + c] = (signed char)(int)rintf(fminf(fmaxf(fmaf(v.x, af.x, af.y), 0.f), 1.614f) * k);
      lds[(w4 + 2) * 144 + c] = (signed char)(int)rintf(fminf(fmaxf(fmaf(v.y, af.x, af.y), 0.f), 1.614f) * k);
      lds[(w4 + 3) * 144 + c] = (signed char)(int)rintf(fminf(fmaxf(fmaf(v.z, af.x, af.y), 0.f), 1.614f) * k);
      lds[(w4 + 4) * 144 + c] = (signed char)(int)rintf(fminf(fmaxf(fmaf(v.w, af.x, af.y), 0.f), 1.614f) * k);
    }
  }
  __syncthreads();
  signed char* dst = apad + (size_t)n * APAD_NSTRIDE;
  for (int i = tid; i < 58 * 8; i += 256) {
    const int col = i >> 3, c16 = i & 7;
    const int pp = hh * 58 + col;
    *(uint4*)(dst + (((size_t)pp * 128 + c16 * 16) ^ ((pp & 7) << 4))) = lds4[col * 9 + c16];
  }
}

// ---------------- conv: block = 128 oc x 224 px (4 rows); act via DMA, weights from L2; 1 barrier ----------------
__global__ __launch_bounds__(256, 2) void conv_k(const signed char* __restrict__ apad,
                                                 const signed char* __restrict__ wq,
                                                 const float* __restrict__ stepp,
                                                 float* __restrict__ out) {
  __shared__ __align__(16) signed char Al[45056];  // 6 padded rows x 58 x 128 (44544B used), XOR-swizzled
  // XCD-bijective swizzle: 448 = 8 XCDs x 56; consecutive vid (same n, adjacent rg) share an XCD L2.
  const int bid = blockIdx.x;
  const int vid = (bid & 7) * 56 + (bid >> 3);
  const int n = vid / 14;
  const int rg = vid - n * 14;
  const int tid = threadIdx.x;
  const int wv = tid >> 6, lane = tid & 63;
  const int lr = lane & 15, q4 = lane >> 4;
  const int kq = q4 * 16;
  const int ohalf = (wv & 1) * 64;
  const int phalf = (wv >> 1) * 112;

  // stage act: 44544 B = 43 full 1KB chunks + one half chunk (lanes 0..31)
  {
    const signed char* gsrc = apad + (size_t)n * APAD_NSTRIDE + (size_t)(rg * 4) * PROWB;
    for (int i = wv; i < 44; i += 4)
      if (i < 43 || lane < 32)
        gload_lds16(gsrc + i * 1024 + lane * 16, Al + i * 1024);
  }

  int pbase[7];
#pragma unroll
  for (int pf = 0; pf < 7; ++pf) {
    const int po = phalf + pf * 16 + lr;   // 0..223
    pbase[pf] = (po / 56) * 58 + po % 56;
  }

  i32x4 acc[7][4];
#pragma unroll
  for (int i = 0; i < 7; ++i)
#pragma unroll
    for (int j = 0; j < 4; ++j) acc[i][j] = (i32x4){0, 0, 0, 0};

  __syncthreads();  // Al ready; only barrier in the kernel

  // K-loop: weight fragments straight from L2, act from swizzled LDS; no barriers
#pragma unroll 3
  for (int rs = 0; rs < 9; ++rs) {
    const int r = rs / 3, s = rs - 3 * r;
    const int poff = r * 58 + s;
    const signed char* wrow = wq + rs * 16384;
#pragma unroll
    for (int k64 = 0; k64 < 2; ++k64) {
      const int kb = k64 * 64 + kq;
      i32x4 wf[4];
#pragma unroll
      for (int of = 0; of < 4; ++of)
        wf[of] = *(const i32x4*)(wrow + (ohalf + of * 16 + lr) * 128 + kb);
#pragma unroll
      for (int pf = 0; pf < 7; ++pf) {
        const int p = pbase[pf] + poff;
        const i32x4 bf = *(const i32x4*)(Al + ((p * 128 + kb) ^ ((p & 7) << 4)));
        acc[pf][0] = __builtin_amdgcn_mfma_i32_16x16x64_i8(wf[0], bf, acc[pf][0], 0, 0, 0);
        acc[pf][1] = __builtin_amdgcn_mfma_i32_16x16x64_i8(wf[1], bf, acc[pf][1], 0, 0, 0);
        acc[pf][2] = __builtin_amdgcn_mfma_i32_16x16x64_i8(wf[2], bf, acc[pf][2], 0, 0, 0);
        acc[pf][3] = __builtin_amdgcn_mfma_i32_16x16x64_i8(wf[3], bf, acc[pf][3], 0, 0, 0);
      }
    }
  }

  const float oscale = 0.269f * stepp[0];  // a_step * w_step/2
  float* outn = out + (size_t)n * NPLANE + (size_t)rg * 224;  // 4-row slab base
#pragma unroll
  for (int pf = 0; pf < 7; ++pf) {
    const int po = phalf + pf * 16 + lr;
    float* op = outn + po;
#pragma unroll
    for (int of = 0; of < 4; ++of) {
      const int oc = ohalf + of * 16 + q4 * 4;
#pragma unroll
      for (int q = 0; q < 4; ++q)
        op[(size_t)(oc + q) * PIX] = (float)acc[pf][of][q] * oscale;
    }
  }
}

extern "C" void kernel_launch(void* const* d_in, const int* in_sizes, int n_in,
                              void* d_out, int out_size, void* d_ws, size_t ws_size,
                              hipStream_t stream) {
  const float* x = (const float*)d_in[0];
  const float* gamma = (const float*)d_in[1];
  const float* beta = (const float*)d_in[2];
  const float* w = (const float*)d_in[3];
  float* out = (float*)d_out;
  char* ws = (char*)d_ws;

  double* bnpart = (double*)(ws);                  // 16384 B
  double* wpart = (double*)(ws + 16384);           // 1024 B
  float* stepp = (float*)(ws + 17408);             // 4 B
  signed char* wq = (signed char*)(ws + 18432);    // 9*128*128 = 147456 B
  signed char* apad = (signed char*)(ws + 196608); // 32*58*58*128 = 13778944 B

  stats_k<<<1088, 256, 0, stream>>>(x, w, bnpart, wpart);
  quant_k<<<dim3(58, 33), 256, 0, stream>>>(x, w, gamma, beta, bnpart, wpart, apad, wq, stepp);
  conv_k<<<448, 256, 0, stream>>>(apad, wq, stepp, out);
}